// Round 3
// baseline (76.541 us; speedup 1.0000x reference)
//
#include <hip/hip_runtime.h>

#define IH 256
#define IW 256
#define NK 512
#define ZTH 3.0f
#define EPSV 1e-8f

// One fused kernel: block = image row. Each block redundantly
// compacts + sorts the ~60 active gaussians (cheap: 21 bitonic stages
// over <=64 elems, fully parallel across 256 blocks) then composites
// its row. Avoids the serial 1-block prep kernel + extra graph node.
__launch_bounds__(256, 4)
__global__ void slice_render_fused(const float* __restrict__ positions,
                                   const float* __restrict__ scales,
                                   const float* __restrict__ opacity,
                                   const float* __restrict__ intensity,
                                   const float* __restrict__ z_target,
                                   float* __restrict__ out) {
    __shared__ float s_pos[3 * NK];   // 6 KB
    __shared__ float s_scl[3 * NK];   // 6 KB
    __shared__ float s_opa[NK];       // 2 KB
    __shared__ float s_int[NK];       // 2 KB
    __shared__ float s_w[NK];         // 2 KB
    __shared__ int   s_idx[NK];       // 2 KB
    __shared__ float s_py[NK], s_isy[NK], s_rowfac[NK], s_it[NK]; // 8 KB
    __shared__ int   s_cnt;

    const int tid = threadIdx.x;
    const float zt = z_target[0];

    // coalesced staging of all inputs into LDS (16 KB total)
    for (int i = tid; i < 3 * NK; i += 256) {
        s_pos[i] = positions[i];
        s_scl[i] = scales[i];
    }
    for (int i = tid; i < NK; i += 256) {
        s_opa[i] = opacity[i];
        s_int[i] = intensity[i];
    }
    if (tid == 0) s_cnt = 0;
    __syncthreads();

    // z-weights; compact active gaussians (arbitrary order — the sort below
    // imposes a deterministic total order (w desc, idx asc) identical to the
    // reference's stable argsort; dropped zero-weight entries contribute 0)
    for (int k = tid; k < NK; k += 256) {
        float zd = (zt - s_pos[3 * k + 2]) / (s_scl[3 * k + 2] + EPSV);
        float w = 0.0f;
        if (fabsf(zd) < ZTH) w = s_opa[k] * __expf(-0.5f * zd * zd);
        if (w > 0.0f) {
            int p = atomicAdd(&s_cnt, 1);
            s_w[p] = w;
            s_idx[p] = k;
        }
    }
    __syncthreads();

    const int m = s_cnt;
    if (m == 0) { out[blockIdx.x * IW + tid] = 0.0f; return; }

    int msort = 2;
    while (msort < m) msort <<= 1;

    // pad to pow2 with sentinels that sort last
    for (int k = m + tid; k < msort; k += 256) { s_w[k] = -1.0f; s_idx[k] = NK; }

    // bitonic sort: descending by w, ties ascending by original index
    const int half = msort >> 1;
    for (int size = 2; size <= msort; size <<= 1) {
        for (int stride = size >> 1; stride > 0; stride >>= 1) {
            __syncthreads();
            for (int p = tid; p < half; p += 256) {
                int i = ((p & ~(stride - 1)) << 1) | (p & (stride - 1));
                int j = i | stride;
                bool desc = ((i & size) == 0);
                float wi = s_w[i], wj = s_w[j];
                int   ii = s_idx[i], ij = s_idx[j];
                bool cb_ji = (wj > wi) || (wj == wi && ij < ii);
                bool cb_ij = (wi > wj) || (wi == wj && ii < ij);
                if (desc ? cb_ji : cb_ij) {
                    s_w[i] = wj;  s_w[j] = wi;
                    s_idx[i] = ij; s_idx[j] = ii;
                }
            }
        }
    }
    __syncthreads();

    // stage sorted params, folding the row-dependent gaussian factor:
    // gauss = exp(-0.5*dxn^2) * exp(-0.5*dyn^2); dxn depends only on the row.
    const float y = (float)blockIdx.x;
    for (int k = tid; k < m; k += 256) {
        int j = s_idx[k];
        float px  = s_pos[3 * j + 0];
        float isx = 1.0f / (s_scl[3 * j + 0] + EPSV);
        float dx  = (y - px) * isx;
        s_rowfac[k] = __expf(-0.5f * dx * dx) * s_w[k];
        s_py[k]   = s_pos[3 * j + 1];
        s_isy[k]  = 1.0f / (s_scl[3 * j + 1] + EPSV);
        s_it[k]   = s_int[j];
    }
    __syncthreads();

    // per-pixel front-to-back compositing
    const float x = (float)tid;
    float T = 1.0f;
    float acc = 0.0f;
    for (int k = 0; k < m; ++k) {
        float dy = (x - s_py[k]) * s_isy[k];
        float a  = fminf(__expf(-0.5f * dy * dy) * s_rowfac[k], 0.99f);
        acc += T * a * s_it[k];
        T   *= 1.0f - a;
        if (__all(T < 1e-6f)) break;   // residual contribution <= 1e-6
    }
    out[blockIdx.x * IW + tid] = acc;
}

extern "C" void kernel_launch(void* const* d_in, const int* in_sizes, int n_in,
                              void* d_out, int out_size, void* d_ws, size_t ws_size,
                              hipStream_t stream) {
    (void)in_sizes; (void)n_in; (void)out_size; (void)d_ws; (void)ws_size;
    const float* positions = (const float*)d_in[0];
    const float* scales    = (const float*)d_in[1];
    const float* opacity   = (const float*)d_in[2];
    const float* intensity = (const float*)d_in[3];
    const float* z_target  = (const float*)d_in[4];
    float* out = (float*)d_out;
    hipLaunchKernelGGL(slice_render_fused, dim3(IH), dim3(256), 0, stream,
                       positions, scales, opacity, intensity, z_target, out);
}

// Round 4
// 69.652 us; speedup vs baseline: 1.0989x; 1.0989x over previous
//
#include <hip/hip_runtime.h>

#define IH 256
#define IW 256
#define NK 512
#define ZTH 3.0f
#define EPSV 1e-8f

// One fused kernel, block = image row. Sort replaced by a barrier-free
// rank sort over the ~60 active gaussians (strict total order: w desc,
// original idx asc == stable jnp.argsort(-eff_w) on the nonzero prefix;
// zero-weight gaussians contribute exactly 0 and are dropped).
// 3 barriers total (vs 23 for the bitonic version) — at 1 block/CU the
// kernel is barrier-latency-bound, so this is the lever.
__launch_bounds__(256, 4)
__global__ void slice_render_fused(const float* __restrict__ positions,
                                   const float* __restrict__ scales,
                                   const float* __restrict__ opacity,
                                   const float* __restrict__ intensity,
                                   const float* __restrict__ z_target,
                                   float* __restrict__ out) {
    __shared__ float  s_w[NK];
    __shared__ int    s_idx[NK];
    __shared__ float4 s_srt[NK + 8];   // {py, 1/sy, rowfac, intensity} sorted
    __shared__ int    s_cnt;

    const int tid = threadIdx.x;
    const float zt = z_target[0];

    if (tid == 0) s_cnt = 0;
    __syncthreads();

    // z-weights + compaction (order arbitrary; rank pass fixes the order).
    // Inputs are 16 KB total and L2-resident across all 256 blocks.
    for (int k = tid; k < NK; k += 256) {
        float zd = (zt - positions[3 * k + 2]) / (scales[3 * k + 2] + EPSV);
        float w = 0.0f;
        if (fabsf(zd) < ZTH) w = opacity[k] * __expf(-0.5f * zd * zd);
        if (w > 0.0f) {
            int p = atomicAdd(&s_cnt, 1);
            s_w[p] = w;
            s_idx[p] = k;
        }
    }
    __syncthreads();

    const int m  = s_cnt;
    const int mp = (m + 7) & ~7;          // pad to unroll granularity
    const float y = (float)blockIdx.x;

    // rank sort + scatter, folding the row-only gaussian factor:
    // gauss = exp(-0.5*dxn^2)*exp(-0.5*dyn^2); dxn depends only on the row.
    for (int i = tid; i < mp; i += 256) {
        if (i < m) {
            float wi = s_w[i];
            int   ji = s_idx[i];
            int rank = 0;
            for (int j = 0; j < m; ++j) {          // broadcast LDS reads
                float wj = s_w[j];
                int   jj = s_idx[j];
                rank += (wj > wi || (wj == wi && jj < ji)) ? 1 : 0;
            }
            float px  = positions[3 * ji + 0];
            float py  = positions[3 * ji + 1];
            float isx = 1.0f / (scales[3 * ji + 0] + EPSV);
            float isy = 1.0f / (scales[3 * ji + 1] + EPSV);
            float dx  = (y - px) * isx;
            float rowfac = __expf(-0.5f * dx * dx) * wi;
            s_srt[rank] = make_float4(py, isy, rowfac, intensity[ji]);
        } else {
            s_srt[i] = make_float4(0.0f, 1.0f, 0.0f, 0.0f);  // alpha == 0 pad
        }
    }
    __syncthreads();

    // per-pixel front-to-back compositing; early-exit checked every 8 iters
    // so the inner body unrolls and pipelines v_exp_f32.
    const float x = (float)tid;
    float T = 1.0f, acc = 0.0f;
    for (int k0 = 0; k0 < mp; k0 += 8) {
#pragma unroll
        for (int u = 0; u < 8; ++u) {
            float4 g = s_srt[k0 + u];              // one ds_read_b128 (broadcast)
            float dy = (x - g.x) * g.y;
            float a  = fminf(__expf(-0.5f * dy * dy) * g.z, 0.99f);
            acc += T * a * g.w;
            T   *= 1.0f - a;
        }
        if (__all(T < 1e-6f)) break;               // residual <= 1e-6
    }
    out[blockIdx.x * IW + tid] = acc;
}

extern "C" void kernel_launch(void* const* d_in, const int* in_sizes, int n_in,
                              void* d_out, int out_size, void* d_ws, size_t ws_size,
                              hipStream_t stream) {
    (void)in_sizes; (void)n_in; (void)out_size; (void)d_ws; (void)ws_size;
    const float* positions = (const float*)d_in[0];
    const float* scales    = (const float*)d_in[1];
    const float* opacity   = (const float*)d_in[2];
    const float* intensity = (const float*)d_in[3];
    const float* z_target  = (const float*)d_in[4];
    float* out = (float*)d_out;
    hipLaunchKernelGGL(slice_render_fused, dim3(IH), dim3(256), 0, stream,
                       positions, scales, opacity, intensity, z_target, out);
}